// Round 7
// baseline (143.486 us; speedup 1.0000x reference)
//
#include <hip/hip_runtime.h>
#include <cstdint>
#include <cstddef>

namespace {

constexpr int Bn   = 8;
constexpr int Cc   = 128;
constexpr int Hh   = 56;
constexpr int Ww   = 56;
constexpr int OUTC = 128;
constexpr int NTAP = 9;
constexpr int HW   = 3136;
constexpr int NPOS = Bn * HW;      // 25088
constexpr int KDIM = 1152;         // Cc*NTAP
constexpr int CH   = Bn * 18 * HW; // partial chunk stride (451584 floats)

constexpr int PT   = 32;           // K2 positions per block
constexpr int CCH  = 64;           // K2 channels per chunk (2 chunks)
constexpr int KC   = CCH * NTAP;   // 576
constexpr int LROW = 584;          // ushort row stride (1168B, 16B-aligned)

constexpr int OFFBLK = 1568;       // offset-conv blocks (4 chunk x 8 b x 49 ijb)
constexpr int WBLK   = 576;        // cwb relayout blocks

typedef __attribute__((ext_vector_type(8))) short  short8v;
typedef __attribute__((ext_vector_type(4))) short  short4v;
typedef __attribute__((ext_vector_type(4))) float  float4v;

__device__ __forceinline__ unsigned short f2bf(float f) {
    union { float f; uint32_t u; } v; v.f = f;
    const uint32_t u = v.u;
    return (unsigned short)((u + 0x7fffu + ((u >> 16) & 1u)) >> 16);  // RNE
}
__device__ __forceinline__ float bf2f(unsigned short us) {
    union { uint32_t u; float f; } v; v.u = (uint32_t)us << 16;
    return v.f;
}

// ---------------------------------------------------------------------------
// R7 DIAGNOSTIC: K1's offset path split out and launched with a DOUBLED grid
// (blocks [1568,3136) recompute blocks [0,1568) and store identical bits —
// benign duplicate stores, no CSE possible across blocks). Purpose: push this
// dispatch to ~74us, above the 43us fill cutoff, so its counters (VALUBusy /
// FETCH_SIZE / Occupancy) finally appear in the top-5 and discriminate the
// three standing stall theories (issue-bound vs HBM-latency vs L2/SMEM
// latency). Body is bitwise-identical R4 math.
// ---------------------------------------------------------------------------
__global__ __launch_bounds__(256) void offset_part_kernel(
        const float* __restrict__ x, const float* __restrict__ ow,
        float* __restrict__ partial) {
    __shared__ float red[4][64 * 18];              // 18.4 KB

    const int blk  = blockIdx.x;
    const int vblk = (blk >= OFFBLK) ? blk - OFFBLK : blk;   // rep=2 duplicate
    const int t    = threadIdx.x;

    const int lane = t & 63;
    const int sq   = __builtin_amdgcn_readfirstlane(t >> 6);   // wave-uniform slice
    const int chunk = vblk & 3;                    // 32-c chunk
    const int pgi  = vblk >> 2;
    const int b    = pgi & 7;
    const int ijb  = (pgi >> 3) * 64;
    const int ij   = ijb + lane;
    const int i    = ij / Ww, j = ij % Ww;
    const float* xb = x + (size_t)b * Cc * HW;

    float acc[18];
#pragma unroll
    for (int m = 0; m < 18; ++m) acc[m] = 0.f;

    const int c0 = chunk * 32 + sq * 8;
    for (int cc = 0; cc < 8; ++cc) {
        const int c = c0 + cc;
        const float* xc = xb + (size_t)c * HW;
        float xv[9];
#pragma unroll
        for (int ky = 0; ky < 3; ++ky) {
            const int y = i + ky - 1;
            const bool yv = (unsigned)y < (unsigned)Hh;
#pragma unroll
            for (int kx = 0; kx < 3; ++kx) {
                const int xx = j + kx - 1;
                xv[ky * 3 + kx] = (yv && (unsigned)xx < (unsigned)Ww) ? xc[y * Ww + xx] : 0.f;
            }
        }
        const float* wc = ow + c * NTAP;           // wave-uniform scalar loads
#pragma unroll
        for (int m = 0; m < 18; ++m) {
#pragma unroll
            for (int tap = 0; tap < 9; ++tap)
                acc[m] = fmaf(wc[m * KDIM + tap], xv[tap], acc[m]);
        }
    }

#pragma unroll
    for (int m = 0; m < 18; ++m) red[sq][lane * 18 + m] = acc[m];
    __syncthreads();

    // m-outer store order (R4): coalesced 64x4B per wave-inst
    float* pout = partial + (size_t)chunk * CH;
    for (int e = t; e < 64 * 18; e += 256) {
        const int m = e >> 6, lpe = e & 63;
        const int idx = lpe * 18 + m;
        const float s01 = red[0][idx] + red[1][idx];
        const float s23 = red[2][idx] + red[3][idx];
        pout[(size_t)(b * 18 + m) * HW + ijb + lpe] = s01 + s23;
    }
}

// ---------------------------------------------------------------------------
// Prep: cwb relayout (blocks [0,576)) + xt plane transpose (blocks [576,968)).
// Verbatim R4 bodies.
// ---------------------------------------------------------------------------
__global__ __launch_bounds__(256) void prep_kernel(
        const float* __restrict__ x, const float* __restrict__ cw,
        unsigned short* __restrict__ cwb, unsigned short* __restrict__ xt) {
    const int blk = blockIdx.x;
    const int t   = threadIdx.x;

    if (blk < WBLK) {                              // weights: 128*1152 elems
        const int i = blk * 256 + t;
        // decompose by cwb layout: i = (((cc*18+ks)*8+wv)*64 + mm*4+quad)*8 + u
        const int u   = i & 7;
        const int mq  = (i >> 3) & 63;             // mm*4+quad
        const int wvv = (i >> 9) & 7;
        const int rest = i >> 12;                  // 0..35
        const int ks = rest % 18, ccg = rest / 18;
        const int mm = mq >> 2, quad = mq & 3;
        const int klocal = ks * 32 + quad * 8 + u;
        const int n = klocal >> 6, cl = klocal & 63;
        const int o = wvv * 16 + mm;
        cwb[i] = f2bf(cw[o * KDIM + (ccg * CCH + cl) * NTAP + n]);
        return;
    }
    // transpose: 392 blocks, 64 pos x 128 ch each -> plane layout
    const int pb2 = blk - WBLK;
    const int b = pb2 & 7;
    const int ijb = (pb2 >> 3) * 64;
    const int lp2 = t & 63, cg = t >> 6;
    const float* xb = x + (size_t)b * Cc * HW + ijb + lp2;
#pragma unroll
    for (int c8 = 0; c8 < 4; ++c8) {
        short8v sv;
#pragma unroll
        for (int u = 0; u < 8; ++u)
            sv[u] = (short)f2bf(xb[(size_t)(cg * 32 + c8 * 8 + u) * HW]);
        const int g16 = cg * 4 + c8;
        *(short8v*)(xt + ((size_t)(b * 16 + g16) * HW + ijb + lp2) * 8) = sv;
    }
}

// ---------------------------------------------------------------------------
// K2: verbatim R2/R4 (measured ~38us in the R2 budget).
// ---------------------------------------------------------------------------
__global__ __launch_bounds__(512, 6) void deform_mfma_kernel(
        const unsigned short* __restrict__ xt, const unsigned short* __restrict__ cwb,
        const float* __restrict__ partial, const float* __restrict__ ob,
        float* __restrict__ out) {
    __shared__ unsigned short xoffB[PT * LROW];    // 36.5 KB
    __shared__ float4v pgS[PT * NTAP];             // {g2,g3,g0,g1}  4.6 KB
    __shared__ int2    poS[PT * NTAP];             // {o2|o3<<16, o0|o1<<16}

    const int t    = threadIdx.x;
    const int lane = t & 63;
    const int mm   = lane & 15, quad = lane >> 4;
    const int wv   = t >> 6;                       // 0..7: 16 out-ch each
    const int lp   = t & 31;                       // staging: pos
    const int grp  = (t >> 5) & 7;                 // staging: 8-ch group
    const int nh   = t >> 8;                       // staging: tap parity (wave-uniform)
    const int blk  = blockIdx.x;
    const int b    = blk & 7;                      // XCD affinity
    const int ijb  = (blk >> 3) * PT;
    const unsigned short* xtb = xt + (size_t)b * 16 * HW * 8;   // per-b plane base

    // ---- params: inline 4-partial combine, then exact fp32 chain ----
    for (int e = t; e < PT * NTAP; e += 512) {
        const int n = e >> 5, lpe = e & 31;
        const int ij = ijb + lpe;
        const size_t iy = (size_t)(b * 18 + n) * HW + ij;
        const size_t ix = (size_t)(b * 18 + 9 + n) * HW + ij;
        float sy = (partial[iy] + partial[CH + iy]) + (partial[2 * CH + iy] + partial[3 * CH + iy]);
        float sx = (partial[ix] + partial[CH + ix]) + (partial[2 * CH + ix] + partial[3 * CH + ix]);
        sy = sy + ob[n];
        sx = sx + ob[9 + n];
        const float py = (float)(ij / Ww + n / 3) + sy;
        const float px = (float)(ij % Ww + n % 3) + sx;
        const float q0y = floorf(py), q0x = floorf(px);
        const float lty = fminf(fmaxf(q0y, 0.f), 57.f);
        const float ltx = fminf(fmaxf(q0x, 0.f), 57.f);
        const float rby = fminf(fmaxf(q0y + 1.f, 0.f), 57.f);
        const float rbx = fminf(fmaxf(q0x + 1.f, 0.f), 57.f);
        const float pyc = fminf(fmaxf(py, 0.f), 57.f);
        const float pxc = fminf(fmaxf(px, 0.f), 57.f);
        float g0 = (1.f - (pyc - lty)) * truncf(1.f - (pxc - ltx));   // lt
        float g1 = (1.f - (rby - pyc)) * truncf(1.f - (rbx - pxc));   // rb
        float g2 = (1.f - (pyc - lty)) * (1.f - (rbx - pxc));         // lb (lty,rbx)
        float g3 = (1.f - (rby - pyc)) * (1.f - (pxc - ltx));         // rt (rby,ltx)
        const int y0 = (int)lty - 1, x0 = (int)ltx - 1;
        const int y1 = (int)rby - 1, x1 = (int)rbx - 1;
        const bool v0y = (unsigned)y0 < (unsigned)Hh, v0x = (unsigned)x0 < (unsigned)Ww;
        const bool v1y = (unsigned)y1 < (unsigned)Hh, v1x = (unsigned)x1 < (unsigned)Ww;
        int o0 = y0 * Ww + x0, o1 = y1 * Ww + x1, o2 = y0 * Ww + x1, o3 = y1 * Ww + x0;
        if (!(v0y && v0x)) { o0 = 0; g0 = 0.f; }
        if (!(v1y && v1x)) { o1 = 0; g1 = 0.f; }
        if (!(v0y && v1x)) { o2 = 0; g2 = 0.f; }
        if (!(v1y && v0x)) { o3 = 0; g3 = 0.f; }
        pgS[e] = (float4v){ g2, g3, g0, g1 };
        poS[e] = make_int2((o2 & 0xffff) | (o3 << 16), (o0 & 0xffff) | (o1 << 16));
    }

    float4v acc[2] = { {0.f,0.f,0.f,0.f}, {0.f,0.f,0.f,0.f} };
    __syncthreads();

    for (int cc = 0; cc < 2; ++cc) {
        if (cc) __syncthreads();
        // ---- branchless staging from xt planes; taps split across halves ----
        const unsigned short* pl = xtb + (size_t)(cc * 8 + grp) * HW * 8;
#pragma unroll
        for (int nn = 0; nn < 5; ++nn) {
            const int n = nn * 2 + nh;             // nh=0: 0,2,4,6,8  nh=1: 1,3,5,7
            if (n < 9) {
                const float4v G = pgS[n * 32 + lp];
                const int2  O = poS[n * 32 + lp];
                const short8v a0 = *(const short8v*)(pl + (size_t)(O.y & 0xffff) * 8);
                const short8v a2 = *(const short8v*)(pl + (size_t)(O.x & 0xffff) * 8);
                const short8v a3 = *(const short8v*)(pl + (size_t)((O.x >> 16) & 0xffff) * 8);
                const short8v a1 = *(const short8v*)(pl + (size_t)((O.y >> 16) & 0xffff) * 8);
                short8v sv;
#pragma unroll
                for (int u = 0; u < 8; ++u) {
                    float v = G.x * bf2f((unsigned short)a2[u]);
                    v = fmaf(G.y, bf2f((unsigned short)a3[u]), v);
                    v = fmaf(G.z, bf2f((unsigned short)a0[u]), v);
                    v = fmaf(G.w, bf2f((unsigned short)a1[u]), v);
                    sv[u] = (short)f2bf(v);
                }
                *(short8v*)&xoffB[lp * LROW + n * CCH + grp * 8] = sv;
            }
        }
        __syncthreads();

        // ---- MFMA GEMM: 18 ks-steps, B from contiguous 1KB streams ----
        const unsigned short* bw = cwb + (size_t)(cc * 144 + wv) * 512 + (mm * 4 + quad) * 8;
        const unsigned short* ap0 = &xoffB[mm * LROW + quad * 8];
#pragma unroll 3
        for (int ks = 0; ks < KC / 32; ++ks) {
            const int kl = ks * 32;
            const short8v b0 = *(const short8v*)(bw + ks * 4096);
#pragma unroll
            for (int pt = 0; pt < 2; ++pt) {
                const unsigned short* ap = ap0 + pt * 16 * LROW + kl;
                const short4v alo = *(const short4v*)ap;
                const short4v ahi = *(const short4v*)(ap + 4);
                const short8v a = __builtin_shufflevector(alo, ahi, 0, 1, 2, 3, 4, 5, 6, 7);
                acc[pt] = __builtin_amdgcn_mfma_f32_16x16x32_bf16(a, b0, acc[pt], 0, 0, 0);
            }
        }
    }

    // ---- epilogue (rows wv*16+mm, layout verified) ----
    float* ob0 = out + (size_t)(b * OUTC + wv * 16 + mm) * HW + ijb + quad * 4;
#pragma unroll
    for (int pt = 0; pt < 2; ++pt)
        *(float4v*)(ob0 + pt * 16) = acc[pt];
}

}  // namespace

extern "C" void kernel_launch(void* const* d_in, const int* in_sizes, int n_in,
                              void* d_out, int out_size, void* d_ws, size_t ws_size,
                              hipStream_t stream) {
    const float* x  = (const float*)d_in[0];   // (8,128,56,56)
    const float* ow = (const float*)d_in[1];   // (18,128,3,3)
    const float* ob = (const float*)d_in[2];   // (18,)
    const float* cw = (const float*)d_in[3];   // (128,128,3,3)
    float* out = (float*)d_out;                // (8,128,56,56)

    char* wsp = (char*)d_ws;
    unsigned short* cwb = (unsigned short*)wsp;                 //    294,912 B
    unsigned short* xt = (unsigned short*)(wsp + 294912);       //  6,422,528 B
    float* partial = (float*)(wsp + 6717440);                   //  7,225,344 B (4 chunks)
                                                                // total 13.94 MB

    offset_part_kernel<<<2 * OFFBLK, 256, 0, stream>>>(x, ow, partial);  // rep=2 diag
    prep_kernel<<<WBLK + 392, 256, 0, stream>>>(x, cw, cwb, xt);
    deform_mfma_kernel<<<NPOS / PT, 512, 0, stream>>>(xt, cwb, partial, ob, out);
}

// Round 8
// 135.605 us; speedup vs baseline: 1.0581x; 1.0581x over previous
//
#include <hip/hip_runtime.h>
#include <cstdint>
#include <cstddef>

namespace {

constexpr int Bn   = 8;
constexpr int Cc   = 128;
constexpr int Hh   = 56;
constexpr int Ww   = 56;
constexpr int OUTC = 128;
constexpr int NTAP = 9;
constexpr int HW   = 3136;
constexpr int NPOS = Bn * HW;      // 25088
constexpr int KDIM = 1152;         // Cc*NTAP
constexpr int CH   = Bn * 18 * HW; // partial chunk stride (451584 floats)

constexpr int PT   = 32;           // K2 positions per block
constexpr int CCH  = 64;           // K2 channels per chunk (2 chunks)
constexpr int KC   = CCH * NTAP;   // 576
constexpr int LROW = 584;          // ushort row stride (1168B, 16B-aligned)

constexpr int WBLK   = 576;        // prep: cwb relayout blocks
constexpr int OFFGRID = 800;       // offset: 4 chunk(high) x 8 b x 25 pos-groups

typedef __attribute__((ext_vector_type(8))) short  short8v;
typedef __attribute__((ext_vector_type(4))) short  short4v;
typedef __attribute__((ext_vector_type(4))) float  float4v;

__device__ __forceinline__ unsigned short f2bf(float f) {
    union { float f; uint32_t u; } v; v.f = f;
    const uint32_t u = v.u;
    return (unsigned short)((u + 0x7fffu + ((u >> 16) & 1u)) >> 16);  // RNE
}
__device__ __forceinline__ float bf2f(unsigned short us) {
    union { uint32_t u; float f; } v; v.u = (uint32_t)us << 16;
    return v.f;
}

// ---------------------------------------------------------------------------
// R8 offset-conv partials. R7 counters: VALUBusy 38% == computed VALU floor
// duty (33%) at 2.6x floor time; FETCH 6.5MB << x size -> stalled on L2/L3
// LATENCY of the per-channel 9-load batches (VGPR=28 tight loop, no load
// pipelining), NOT s_load count (R5 falsified) and NOT occupancy (R1).
// Fix: (a) P=2 adjacent-position pairs per lane — pairs never cross rows
// (Ww=56 even), tap windows overlap (12 loads serve 2 positions), every
// scalar weight feeds 2 FMAs; (b) channel-unroll x2 — 24 loads in flight
// before each FMA block. FMA order per position/channel is IDENTICAL to R4
// -> bitwise-same partials. Block = 128 pos x 32 ch (4 wave-slices);
// grid = chunk(high; co-resident blocks share one 20.7KB weight slice)
// x 8 b x 25 pg = 800.
// ---------------------------------------------------------------------------
__global__ __launch_bounds__(256) void offset_part_kernel(
        const float* __restrict__ x, const float* __restrict__ ow,
        float* __restrict__ partial) {
    __shared__ float red[4][128 * 18];             // 36.9 KB

    const int t    = threadIdx.x;
    const int lane = t & 63;
    const int sq   = __builtin_amdgcn_readfirstlane(t >> 6);   // wave-uniform slice
    const int blk  = blockIdx.x;
    const int chunk = blk / 200;                   // high bits: weight-K$ sharing
    const int rem   = blk % 200;
    const int b     = rem / 25;
    const int pg    = rem % 25;                    // 3136 = 24*128 + 64
    const int ijb   = pg * 128;

    const int ij0 = ijb + 2 * lane;                // lane owns (ij0, ij0+1)
    const bool pv = ij0 < HW;                      // tail guard (pg==24, lane>=32)
    const int irow = ij0 / Ww, jc0 = ij0 % Ww;     // jc0 even; pair in one row
    const float* xb = x + (size_t)b * Cc * HW;

    float acc0[18], acc1[18];
#pragma unroll
    for (int m = 0; m < 18; ++m) { acc0[m] = 0.f; acc1[m] = 0.f; }

    const int c0 = chunk * 32 + sq * 8;
    for (int cc = 0; cc < 8; cc += 2) {
        // ---- load both channels' 3x4 windows first (24 loads in flight) ----
        float xwA[12], xwB[12];
        const float* xcA = xb + (size_t)(c0 + cc) * HW;
        const float* xcB = xb + (size_t)(c0 + cc + 1) * HW;
#pragma unroll
        for (int ky = 0; ky < 3; ++ky) {
            const int y = irow + ky - 1;
            const bool yv = pv && ((unsigned)y < (unsigned)Hh);
#pragma unroll
            for (int kx = 0; kx < 4; ++kx) {
                const int xx = jc0 + kx - 1;
                const bool v = yv && ((unsigned)xx < (unsigned)Ww);
                xwA[ky * 4 + kx] = v ? xcA[y * Ww + xx] : 0.f;
                xwB[ky * 4 + kx] = v ? xcB[y * Ww + xx] : 0.f;
            }
        }
        // ---- FMA chains: channel cc fully, then cc+1 (same order as R4) ----
        const float* wcA = ow + (c0 + cc) * NTAP;
        const float* wcB = wcA + NTAP;
#pragma unroll
        for (int m = 0; m < 18; ++m) {
#pragma unroll
            for (int tap = 0; tap < 9; ++tap) {
                const float w = wcA[m * KDIM + tap];
                const int xi = (tap / 3) * 4 + (tap % 3);
                acc0[m] = fmaf(w, xwA[xi], acc0[m]);
                acc1[m] = fmaf(w, xwA[xi + 1], acc1[m]);
            }
        }
#pragma unroll
        for (int m = 0; m < 18; ++m) {
#pragma unroll
            for (int tap = 0; tap < 9; ++tap) {
                const float w = wcB[m * KDIM + tap];
                const int xi = (tap / 3) * 4 + (tap % 3);
                acc0[m] = fmaf(w, xwB[xi], acc0[m]);
                acc1[m] = fmaf(w, xwB[xi + 1], acc1[m]);
            }
        }
    }

    // red layout [m*128 + p]: stores 2 adjacent dwords/lane, reads coalesced
#pragma unroll
    for (int m = 0; m < 18; ++m) {
        red[sq][m * 128 + 2 * lane]     = acc0[m];
        red[sq][m * 128 + 2 * lane + 1] = acc1[m];
    }
    __syncthreads();

    float* pout = partial + (size_t)chunk * CH;
    for (int e = t; e < 128 * 18; e += 256) {
        const int m = e >> 7, p = e & 127;         // idx == e (layout m*128+p)
        if (ijb + p < HW) {
            const float s01 = red[0][e] + red[1][e];
            const float s23 = red[2][e] + red[3][e];
            pout[(size_t)(b * 18 + m) * HW + ijb + p] = s01 + s23;
        }
    }
}

// ---------------------------------------------------------------------------
// Prep: cwb relayout (blocks [0,576)) + xt plane transpose (blocks [576,968)).
// Verbatim R4/R7 bodies.
// ---------------------------------------------------------------------------
__global__ __launch_bounds__(256) void prep_kernel(
        const float* __restrict__ x, const float* __restrict__ cw,
        unsigned short* __restrict__ cwb, unsigned short* __restrict__ xt) {
    const int blk = blockIdx.x;
    const int t   = threadIdx.x;

    if (blk < WBLK) {                              // weights: 128*1152 elems
        const int i = blk * 256 + t;
        // decompose by cwb layout: i = (((cc*18+ks)*8+wv)*64 + mm*4+quad)*8 + u
        const int u   = i & 7;
        const int mq  = (i >> 3) & 63;             // mm*4+quad
        const int wvv = (i >> 9) & 7;
        const int rest = i >> 12;                  // 0..35
        const int ks = rest % 18, ccg = rest / 18;
        const int mm = mq >> 2, quad = mq & 3;
        const int klocal = ks * 32 + quad * 8 + u;
        const int n = klocal >> 6, cl = klocal & 63;
        const int o = wvv * 16 + mm;
        cwb[i] = f2bf(cw[o * KDIM + (ccg * CCH + cl) * NTAP + n]);
        return;
    }
    // transpose: 392 blocks, 64 pos x 128 ch each -> plane layout
    const int pb2 = blk - WBLK;
    const int b = pb2 & 7;
    const int ijb = (pb2 >> 3) * 64;
    const int lp2 = t & 63, cg = t >> 6;
    const float* xb = x + (size_t)b * Cc * HW + ijb + lp2;
#pragma unroll
    for (int c8 = 0; c8 < 4; ++c8) {
        short8v sv;
#pragma unroll
        for (int u = 0; u < 8; ++u)
            sv[u] = (short)f2bf(xb[(size_t)(cg * 32 + c8 * 8 + u) * HW]);
        const int g16 = cg * 4 + c8;
        *(short8v*)(xt + ((size_t)(b * 16 + g16) * HW + ijb + lp2) * 8) = sv;
    }
}

// ---------------------------------------------------------------------------
// K2: verbatim R2/R4 (measured ~38us in the R2 budget).
// ---------------------------------------------------------------------------
__global__ __launch_bounds__(512, 6) void deform_mfma_kernel(
        const unsigned short* __restrict__ xt, const unsigned short* __restrict__ cwb,
        const float* __restrict__ partial, const float* __restrict__ ob,
        float* __restrict__ out) {
    __shared__ unsigned short xoffB[PT * LROW];    // 36.5 KB
    __shared__ float4v pgS[PT * NTAP];             // {g2,g3,g0,g1}  4.6 KB
    __shared__ int2    poS[PT * NTAP];             // {o2|o3<<16, o0|o1<<16}

    const int t    = threadIdx.x;
    const int lane = t & 63;
    const int mm   = lane & 15, quad = lane >> 4;
    const int wv   = t >> 6;                       // 0..7: 16 out-ch each
    const int lp   = t & 31;                       // staging: pos
    const int grp  = (t >> 5) & 7;                 // staging: 8-ch group
    const int nh   = t >> 8;                       // staging: tap parity (wave-uniform)
    const int blk  = blockIdx.x;
    const int b    = blk & 7;                      // XCD affinity
    const int ijb  = (blk >> 3) * PT;
    const unsigned short* xtb = xt + (size_t)b * 16 * HW * 8;   // per-b plane base

    // ---- params: inline 4-partial combine, then exact fp32 chain ----
    for (int e = t; e < PT * NTAP; e += 512) {
        const int n = e >> 5, lpe = e & 31;
        const int ij = ijb + lpe;
        const size_t iy = (size_t)(b * 18 + n) * HW + ij;
        const size_t ix = (size_t)(b * 18 + 9 + n) * HW + ij;
        float sy = (partial[iy] + partial[CH + iy]) + (partial[2 * CH + iy] + partial[3 * CH + iy]);
        float sx = (partial[ix] + partial[CH + ix]) + (partial[2 * CH + ix] + partial[3 * CH + ix]);
        sy = sy + ob[n];
        sx = sx + ob[9 + n];
        const float py = (float)(ij / Ww + n / 3) + sy;
        const float px = (float)(ij % Ww + n % 3) + sx;
        const float q0y = floorf(py), q0x = floorf(px);
        const float lty = fminf(fmaxf(q0y, 0.f), 57.f);
        const float ltx = fminf(fmaxf(q0x, 0.f), 57.f);
        const float rby = fminf(fmaxf(q0y + 1.f, 0.f), 57.f);
        const float rbx = fminf(fmaxf(q0x + 1.f, 0.f), 57.f);
        const float pyc = fminf(fmaxf(py, 0.f), 57.f);
        const float pxc = fminf(fmaxf(px, 0.f), 57.f);
        float g0 = (1.f - (pyc - lty)) * truncf(1.f - (pxc - ltx));   // lt
        float g1 = (1.f - (rby - pyc)) * truncf(1.f - (rbx - pxc));   // rb
        float g2 = (1.f - (pyc - lty)) * (1.f - (rbx - pxc));         // lb (lty,rbx)
        float g3 = (1.f - (rby - pyc)) * (1.f - (pxc - ltx));         // rt (rby,ltx)
        const int y0 = (int)lty - 1, x0 = (int)ltx - 1;
        const int y1 = (int)rby - 1, x1 = (int)rbx - 1;
        const bool v0y = (unsigned)y0 < (unsigned)Hh, v0x = (unsigned)x0 < (unsigned)Ww;
        const bool v1y = (unsigned)y1 < (unsigned)Hh, v1x = (unsigned)x1 < (unsigned)Ww;
        int o0 = y0 * Ww + x0, o1 = y1 * Ww + x1, o2 = y0 * Ww + x1, o3 = y1 * Ww + x0;
        if (!(v0y && v0x)) { o0 = 0; g0 = 0.f; }
        if (!(v1y && v1x)) { o1 = 0; g1 = 0.f; }
        if (!(v0y && v1x)) { o2 = 0; g2 = 0.f; }
        if (!(v1y && v0x)) { o3 = 0; g3 = 0.f; }
        pgS[e] = (float4v){ g2, g3, g0, g1 };
        poS[e] = make_int2((o2 & 0xffff) | (o3 << 16), (o0 & 0xffff) | (o1 << 16));
    }

    float4v acc[2] = { {0.f,0.f,0.f,0.f}, {0.f,0.f,0.f,0.f} };
    __syncthreads();

    for (int cc = 0; cc < 2; ++cc) {
        if (cc) __syncthreads();
        // ---- branchless staging from xt planes; taps split across halves ----
        const unsigned short* pl = xtb + (size_t)(cc * 8 + grp) * HW * 8;
#pragma unroll
        for (int nn = 0; nn < 5; ++nn) {
            const int n = nn * 2 + nh;             // nh=0: 0,2,4,6,8  nh=1: 1,3,5,7
            if (n < 9) {
                const float4v G = pgS[n * 32 + lp];
                const int2  O = poS[n * 32 + lp];
                const short8v a0 = *(const short8v*)(pl + (size_t)(O.y & 0xffff) * 8);
                const short8v a2 = *(const short8v*)(pl + (size_t)(O.x & 0xffff) * 8);
                const short8v a3 = *(const short8v*)(pl + (size_t)((O.x >> 16) & 0xffff) * 8);
                const short8v a1 = *(const short8v*)(pl + (size_t)((O.y >> 16) & 0xffff) * 8);
                short8v sv;
#pragma unroll
                for (int u = 0; u < 8; ++u) {
                    float v = G.x * bf2f((unsigned short)a2[u]);
                    v = fmaf(G.y, bf2f((unsigned short)a3[u]), v);
                    v = fmaf(G.z, bf2f((unsigned short)a0[u]), v);
                    v = fmaf(G.w, bf2f((unsigned short)a1[u]), v);
                    sv[u] = (short)f2bf(v);
                }
                *(short8v*)&xoffB[lp * LROW + n * CCH + grp * 8] = sv;
            }
        }
        __syncthreads();

        // ---- MFMA GEMM: 18 ks-steps, B from contiguous 1KB streams ----
        const unsigned short* bw = cwb + (size_t)(cc * 144 + wv) * 512 + (mm * 4 + quad) * 8;
        const unsigned short* ap0 = &xoffB[mm * LROW + quad * 8];
#pragma unroll 3
        for (int ks = 0; ks < KC / 32; ++ks) {
            const int kl = ks * 32;
            const short8v b0 = *(const short8v*)(bw + ks * 4096);
#pragma unroll
            for (int pt = 0; pt < 2; ++pt) {
                const unsigned short* ap = ap0 + pt * 16 * LROW + kl;
                const short4v alo = *(const short4v*)ap;
                const short4v ahi = *(const short4v*)(ap + 4);
                const short8v a = __builtin_shufflevector(alo, ahi, 0, 1, 2, 3, 4, 5, 6, 7);
                acc[pt] = __builtin_amdgcn_mfma_f32_16x16x32_bf16(a, b0, acc[pt], 0, 0, 0);
            }
        }
    }

    // ---- epilogue (rows wv*16+mm, layout verified) ----
    float* ob0 = out + (size_t)(b * OUTC + wv * 16 + mm) * HW + ijb + quad * 4;
#pragma unroll
    for (int pt = 0; pt < 2; ++pt)
        *(float4v*)(ob0 + pt * 16) = acc[pt];
}

}  // namespace

extern "C" void kernel_launch(void* const* d_in, const int* in_sizes, int n_in,
                              void* d_out, int out_size, void* d_ws, size_t ws_size,
                              hipStream_t stream) {
    const float* x  = (const float*)d_in[0];   // (8,128,56,56)
    const float* ow = (const float*)d_in[1];   // (18,128,3,3)
    const float* ob = (const float*)d_in[2];   // (18,)
    const float* cw = (const float*)d_in[3];   // (128,128,3,3)
    float* out = (float*)d_out;                // (8,128,56,56)

    char* wsp = (char*)d_ws;
    unsigned short* cwb = (unsigned short*)wsp;                 //    294,912 B
    unsigned short* xt = (unsigned short*)(wsp + 294912);       //  6,422,528 B
    float* partial = (float*)(wsp + 6717440);                   //  7,225,344 B (4 chunks)
                                                                // total 13.94 MB

    offset_part_kernel<<<OFFGRID, 256, 0, stream>>>(x, ow, partial);
    prep_kernel<<<WBLK + 392, 256, 0, stream>>>(x, cw, cwb, xt);
    deform_mfma_kernel<<<NPOS / PT, 512, 0, stream>>>(xt, cwb, partial, ob, out);
}

// Round 9
// 126.895 us; speedup vs baseline: 1.1307x; 1.0686x over previous
//
#include <hip/hip_runtime.h>
#include <cstdint>
#include <cstddef>

namespace {

constexpr int Bn   = 8;
constexpr int Cc   = 128;
constexpr int Hh   = 56;
constexpr int Ww   = 56;
constexpr int OUTC = 128;
constexpr int NTAP = 9;
constexpr int HW   = 3136;
constexpr int NPOS = Bn * HW;      // 25088
constexpr int KDIM = 1152;         // Cc*NTAP
constexpr int CH   = Bn * 18 * HW; // partial chunk stride (451584 floats)

constexpr int PT   = 32;           // K2 positions per block
constexpr int CCH  = 64;           // K2 channels per chunk (2 chunks)
constexpr int KC   = CCH * NTAP;   // 576
constexpr int LROW = 584;          // ushort row stride (1168B, 16B-aligned)

constexpr int OFFBLK = 1568;       // K1: offset-conv blocks
constexpr int WBLK   = 576;        // K1: cwb relayout blocks

typedef __attribute__((ext_vector_type(8))) short  short8v;
typedef __attribute__((ext_vector_type(4))) short  short4v;
typedef __attribute__((ext_vector_type(4))) float  float4v;

__device__ __forceinline__ unsigned short f2bf(float f) {
    union { float f; uint32_t u; } v; v.f = f;
    const uint32_t u = v.u;
    return (unsigned short)((u + 0x7fffu + ((u >> 16) & 1u)) >> 16);  // RNE
}
__device__ __forceinline__ float bf2f(unsigned short us) {
    union { uint32_t u; float f; } v; v.u = (uint32_t)us << 16;
    return v.f;
}

// ---------------------------------------------------------------------------
// K1: fused offset-conv partials + cwb relayout + xt transpose.
// Structure is R4's (best measured, 125.0us total). R9 change: the offset
// cc-loop software-prefetches the NEXT channel's 9-element window into regs
// before the current 162-FMA chain (R7 counters: VALU duty 38%, VGPR=28 —
// rolled loop serialized {9 loads -> wait -> FMAs} on L2 latency). Prefetch
// overlaps the ~300cy load latency with 324cy of FMA issue. +~18 VGPR
// (~46 total, <=64 -> 8 waves/SIMD kept; R8's regression was occupancy/spill
// from oversized per-thread state). FMA order bitwise identical.
// Block ranges:
//   [0, 1568)            offset-conv chunk partials (4 chunks x 32ch)
//   [1568, 2144)         cwb bf16 fragment-contiguous relayout
//   [2144, 2536)         x -> xt bf16 plane transpose [b][g16][ij][8ch]
// ---------------------------------------------------------------------------
__global__ __launch_bounds__(256) void fused_prep_offset_kernel(
        const float* __restrict__ x, const float* __restrict__ ow,
        const float* __restrict__ cw,
        unsigned short* __restrict__ cwb, unsigned short* __restrict__ xt,
        float* __restrict__ partial) {
    __shared__ float red[4][64 * 18];              // 18.4 KB (offset path only)

    const int blk = blockIdx.x;
    const int t   = threadIdx.x;

    if (blk >= OFFBLK) {
        const int pb = blk - OFFBLK;
        if (pb < WBLK) {                           // weights: 128*1152 elems
            const int i = pb * 256 + t;
            // decompose by cwb layout: i = (((cc*18+ks)*8+wv)*64 + mm*4+quad)*8 + u
            const int u   = i & 7;
            const int mq  = (i >> 3) & 63;         // mm*4+quad
            const int wvv = (i >> 9) & 7;
            const int rest = i >> 12;              // 0..35
            const int ks = rest % 18, ccg = rest / 18;
            const int mm = mq >> 2, quad = mq & 3;
            const int klocal = ks * 32 + quad * 8 + u;
            const int n = klocal >> 6, cl = klocal & 63;
            const int o = wvv * 16 + mm;
            cwb[i] = f2bf(cw[o * KDIM + (ccg * CCH + cl) * NTAP + n]);
            return;
        }
        // transpose: 392 blocks, 64 pos x 128 ch each -> plane layout
        const int pb2 = pb - WBLK;
        const int b = pb2 & 7;
        const int ijb = (pb2 >> 3) * 64;
        const int lp2 = t & 63, cg = t >> 6;
        const float* xb = x + (size_t)b * Cc * HW + ijb + lp2;
#pragma unroll
        for (int c8 = 0; c8 < 4; ++c8) {
            short8v sv;
#pragma unroll
            for (int u = 0; u < 8; ++u)
                sv[u] = (short)f2bf(xb[(size_t)(cg * 32 + c8 * 8 + u) * HW]);
            const int g16 = cg * 4 + c8;
            *(short8v*)(xt + ((size_t)(b * 16 + g16) * HW + ijb + lp2) * 8) = sv;
        }
        return;
    }

    // ---- offset-conv chunk partials (R4 decode; R9 prefetched cc-loop) ----
    const int lane = t & 63;
    const int sq   = __builtin_amdgcn_readfirstlane(t >> 6);   // wave-uniform slice
    const int chunk = blk & 3;                     // 32-c chunk
    const int pgi  = blk >> 2;
    const int b    = pgi & 7;
    const int ijb  = (pgi >> 3) * 64;
    const int ij   = ijb + lane;
    const int i    = ij / Ww, j = ij % Ww;
    const float* xb = x + (size_t)b * Cc * HW;

    float acc[18];
#pragma unroll
    for (int m = 0; m < 18; ++m) acc[m] = 0.f;

    const int c0 = chunk * 32 + sq * 8;

    // window-load helper (bounds folded; values identical to R4's)
    auto loadwin = [&](float* w, int c) {
        const float* xc = xb + (size_t)c * HW;
#pragma unroll
        for (int ky = 0; ky < 3; ++ky) {
            const int y = i + ky - 1;
            const bool yv = (unsigned)y < (unsigned)Hh;
#pragma unroll
            for (int kx = 0; kx < 3; ++kx) {
                const int xx = j + kx - 1;
                w[ky * 3 + kx] = (yv && (unsigned)xx < (unsigned)Ww) ? xc[y * Ww + xx] : 0.f;
            }
        }
    };

    float xv[9];
    loadwin(xv, c0);
    for (int cc = 0; cc < 8; ++cc) {
        float xn[9];
        if (cc < 7) loadwin(xn, c0 + cc + 1);      // prefetch next window NOW
        const float* wc = ow + (c0 + cc) * NTAP;   // wave-uniform scalar loads
#pragma unroll
        for (int m = 0; m < 18; ++m) {
#pragma unroll
            for (int tap = 0; tap < 9; ++tap)
                acc[m] = fmaf(wc[m * KDIM + tap], xv[tap], acc[m]);
        }
        if (cc < 7) {
#pragma unroll
            for (int q = 0; q < 9; ++q) xv[q] = xn[q];
        }
    }

#pragma unroll
    for (int m = 0; m < 18; ++m) red[sq][lane * 18 + m] = acc[m];
    __syncthreads();

    // ---- m-outer store order (R4): coalesced 64x4B per wave-inst ----
    float* pout = partial + (size_t)chunk * CH;
    for (int e = t; e < 64 * 18; e += 256) {
        const int m = e >> 6, lpe = e & 63;        // wave: one m, 64 consecutive ij
        const int idx = lpe * 18 + m;
        const float s01 = red[0][idx] + red[1][idx];
        const float s23 = red[2][idx] + red[3][idx];
        pout[(size_t)(b * 18 + m) * HW + ijb + lpe] = s01 + s23;
    }
}

// ---------------------------------------------------------------------------
// K2: verbatim R2/R4 (measured ~38us in the R2 budget).
// ---------------------------------------------------------------------------
__global__ __launch_bounds__(512, 6) void deform_mfma_kernel(
        const unsigned short* __restrict__ xt, const unsigned short* __restrict__ cwb,
        const float* __restrict__ partial, const float* __restrict__ ob,
        float* __restrict__ out) {
    __shared__ unsigned short xoffB[PT * LROW];    // 36.5 KB
    __shared__ float4v pgS[PT * NTAP];             // {g2,g3,g0,g1}  4.6 KB
    __shared__ int2    poS[PT * NTAP];             // {o2|o3<<16, o0|o1<<16}

    const int t    = threadIdx.x;
    const int lane = t & 63;
    const int mm   = lane & 15, quad = lane >> 4;
    const int wv   = t >> 6;                       // 0..7: 16 out-ch each
    const int lp   = t & 31;                       // staging: pos
    const int grp  = (t >> 5) & 7;                 // staging: 8-ch group
    const int nh   = t >> 8;                       // staging: tap parity (wave-uniform)
    const int blk  = blockIdx.x;
    const int b    = blk & 7;                      // XCD affinity
    const int ijb  = (blk >> 3) * PT;
    const unsigned short* xtb = xt + (size_t)b * 16 * HW * 8;   // per-b plane base

    // ---- params: inline 4-partial combine, then exact fp32 chain ----
    for (int e = t; e < PT * NTAP; e += 512) {
        const int n = e >> 5, lpe = e & 31;
        const int ij = ijb + lpe;
        const size_t iy = (size_t)(b * 18 + n) * HW + ij;
        const size_t ix = (size_t)(b * 18 + 9 + n) * HW + ij;
        float sy = (partial[iy] + partial[CH + iy]) + (partial[2 * CH + iy] + partial[3 * CH + iy]);
        float sx = (partial[ix] + partial[CH + ix]) + (partial[2 * CH + ix] + partial[3 * CH + ix]);
        sy = sy + ob[n];
        sx = sx + ob[9 + n];
        const float py = (float)(ij / Ww + n / 3) + sy;
        const float px = (float)(ij % Ww + n % 3) + sx;
        const float q0y = floorf(py), q0x = floorf(px);
        const float lty = fminf(fmaxf(q0y, 0.f), 57.f);
        const float ltx = fminf(fmaxf(q0x, 0.f), 57.f);
        const float rby = fminf(fmaxf(q0y + 1.f, 0.f), 57.f);
        const float rbx = fminf(fmaxf(q0x + 1.f, 0.f), 57.f);
        const float pyc = fminf(fmaxf(py, 0.f), 57.f);
        const float pxc = fminf(fmaxf(px, 0.f), 57.f);
        float g0 = (1.f - (pyc - lty)) * truncf(1.f - (pxc - ltx));   // lt
        float g1 = (1.f - (rby - pyc)) * truncf(1.f - (rbx - pxc));   // rb
        float g2 = (1.f - (pyc - lty)) * (1.f - (rbx - pxc));         // lb (lty,rbx)
        float g3 = (1.f - (rby - pyc)) * (1.f - (pxc - ltx));         // rt (rby,ltx)
        const int y0 = (int)lty - 1, x0 = (int)ltx - 1;
        const int y1 = (int)rby - 1, x1 = (int)rbx - 1;
        const bool v0y = (unsigned)y0 < (unsigned)Hh, v0x = (unsigned)x0 < (unsigned)Ww;
        const bool v1y = (unsigned)y1 < (unsigned)Hh, v1x = (unsigned)x1 < (unsigned)Ww;
        int o0 = y0 * Ww + x0, o1 = y1 * Ww + x1, o2 = y0 * Ww + x1, o3 = y1 * Ww + x0;
        if (!(v0y && v0x)) { o0 = 0; g0 = 0.f; }
        if (!(v1y && v1x)) { o1 = 0; g1 = 0.f; }
        if (!(v0y && v1x)) { o2 = 0; g2 = 0.f; }
        if (!(v1y && v0x)) { o3 = 0; g3 = 0.f; }
        pgS[e] = (float4v){ g2, g3, g0, g1 };
        poS[e] = make_int2((o2 & 0xffff) | (o3 << 16), (o0 & 0xffff) | (o1 << 16));
    }

    float4v acc[2] = { {0.f,0.f,0.f,0.f}, {0.f,0.f,0.f,0.f} };
    __syncthreads();

    for (int cc = 0; cc < 2; ++cc) {
        if (cc) __syncthreads();
        // ---- branchless staging from xt planes; taps split across halves ----
        const unsigned short* pl = xtb + (size_t)(cc * 8 + grp) * HW * 8;
#pragma unroll
        for (int nn = 0; nn < 5; ++nn) {
            const int n = nn * 2 + nh;             // nh=0: 0,2,4,6,8  nh=1: 1,3,5,7
            if (n < 9) {
                const float4v G = pgS[n * 32 + lp];
                const int2  O = poS[n * 32 + lp];
                const short8v a0 = *(const short8v*)(pl + (size_t)(O.y & 0xffff) * 8);
                const short8v a2 = *(const short8v*)(pl + (size_t)(O.x & 0xffff) * 8);
                const short8v a3 = *(const short8v*)(pl + (size_t)((O.x >> 16) & 0xffff) * 8);
                const short8v a1 = *(const short8v*)(pl + (size_t)((O.y >> 16) & 0xffff) * 8);
                short8v sv;
#pragma unroll
                for (int u = 0; u < 8; ++u) {
                    float v = G.x * bf2f((unsigned short)a2[u]);
                    v = fmaf(G.y, bf2f((unsigned short)a3[u]), v);
                    v = fmaf(G.z, bf2f((unsigned short)a0[u]), v);
                    v = fmaf(G.w, bf2f((unsigned short)a1[u]), v);
                    sv[u] = (short)f2bf(v);
                }
                *(short8v*)&xoffB[lp * LROW + n * CCH + grp * 8] = sv;
            }
        }
        __syncthreads();

        // ---- MFMA GEMM: 18 ks-steps, B from contiguous 1KB streams ----
        const unsigned short* bw = cwb + (size_t)(cc * 144 + wv) * 512 + (mm * 4 + quad) * 8;
        const unsigned short* ap0 = &xoffB[mm * LROW + quad * 8];
#pragma unroll 3
        for (int ks = 0; ks < KC / 32; ++ks) {
            const int kl = ks * 32;
            const short8v b0 = *(const short8v*)(bw + ks * 4096);
#pragma unroll
            for (int pt = 0; pt < 2; ++pt) {
                const unsigned short* ap = ap0 + pt * 16 * LROW + kl;
                const short4v alo = *(const short4v*)ap;
                const short4v ahi = *(const short4v*)(ap + 4);
                const short8v a = __builtin_shufflevector(alo, ahi, 0, 1, 2, 3, 4, 5, 6, 7);
                acc[pt] = __builtin_amdgcn_mfma_f32_16x16x32_bf16(a, b0, acc[pt], 0, 0, 0);
            }
        }
    }

    // ---- epilogue (rows wv*16+mm, layout verified) ----
    float* ob0 = out + (size_t)(b * OUTC + wv * 16 + mm) * HW + ijb + quad * 4;
#pragma unroll
    for (int pt = 0; pt < 2; ++pt)
        *(float4v*)(ob0 + pt * 16) = acc[pt];
}

}  // namespace

extern "C" void kernel_launch(void* const* d_in, const int* in_sizes, int n_in,
                              void* d_out, int out_size, void* d_ws, size_t ws_size,
                              hipStream_t stream) {
    const float* x  = (const float*)d_in[0];   // (8,128,56,56)
    const float* ow = (const float*)d_in[1];   // (18,128,3,3)
    const float* ob = (const float*)d_in[2];   // (18,)
    const float* cw = (const float*)d_in[3];   // (128,128,3,3)
    float* out = (float*)d_out;                // (8,128,56,56)

    char* wsp = (char*)d_ws;
    unsigned short* cwb = (unsigned short*)wsp;                 //    294,912 B
    unsigned short* xt = (unsigned short*)(wsp + 294912);       //  6,422,528 B
    float* partial = (float*)(wsp + 6717440);                   //  7,225,344 B (4 chunks)
                                                                // total 13.94 MB

    fused_prep_offset_kernel<<<OFFBLK + WBLK + 392, 256, 0, stream>>>(
        x, ow, cw, cwb, xt, partial);
    deform_mfma_kernel<<<NPOS / PT, 512, 0, stream>>>(xt, cwb, partial, ob, out);
}